// Round 6
// baseline (1254.727 us; speedup 1.0000x reference)
//
#include <hip/hip_runtime.h>

// Diagonal RNN scan: h_t = a_p * h_{t-1} + x_t,  a_p = 1 - relu(w_p), h_{-1}=0.
// x (B=32, L=8192, P=128) fp32, w (P,) fp32, out (B,L,P) fp32.
// R6: single-pass decoupled lookback. Each block: load 128-timestep slice to
// registers -> publish block aggregate (release) -> wait predecessors' flags
// -> accumulate seed (combine factor a^128, parallel depth 1) -> emit.
// x read ONCE, out written once: ~256 MB total HBM traffic.

typedef float f4 __attribute__((ext_vector_type(4)));

#define BB 32
#define LL 8192
#define PP 128
#define CHUNK 16                 // timesteps per 32-lane group
#define GPB 8                    // groups per block
#define BSTEPS (CHUNK * GPB)     // 128 timesteps per block
#define BPR (LL / BSTEPS)        // 64 blocks per batch-row
#define GRID (BB * BPR)          // 2048 blocks

__global__ __launch_bounds__(256) void k_scan(
    const float* __restrict__ x, const float* __restrict__ w,
    float* __restrict__ agg /* [B][BPR][P] */, int* __restrict__ flags /* [B][BPR] */,
    float* __restrict__ out) {
  const int tid = threadIdx.x;
  const int g = tid >> 5;   // group -> chunk within block
  const int l = tid & 31;   // lane -> float4 index over P
  const int b = blockIdx.x / BPR;
  const int cg = blockIdx.x % BPR;
  const int c = cg * GPB + g;

  const f4 w4 = reinterpret_cast<const f4*>(w)[l];
  f4 a4;
  a4.x = 1.0f - fmaxf(w4.x, 0.0f);
  a4.y = 1.0f - fmaxf(w4.y, 0.0f);
  a4.z = 1.0f - fmaxf(w4.z, 0.0f);
  a4.w = 1.0f - fmaxf(w4.w, 0.0f);

  const size_t off = ((size_t)b * LL + (size_t)c * CHUNK) * (PP / 4) + l;
  const f4* xv = reinterpret_cast<const f4*>(x) + off;

  // Phase 1: load slice into registers; compute group-local final.
  f4 xr[CHUNK];
#pragma unroll
  for (int t = 0; t < CHUNK; ++t)
    xr[t] = __builtin_nontemporal_load(&xv[(size_t)t * (PP / 4)]);

  f4 h = (f4)(0.0f);
#pragma unroll
  for (int t = 0; t < CHUNK; ++t) {
    h.x = fmaf(a4.x, h.x, xr[t].x);
    h.y = fmaf(a4.y, h.y, xr[t].y);
    h.z = fmaf(a4.z, h.z, xr[t].z);
    h.w = fmaf(a4.w, h.w, xr[t].w);
  }

  __shared__ float sf[GPB][PP];
  __shared__ float seed[GPB][PP];
  reinterpret_cast<f4*>(&sf[g][0])[l] = h;
  __syncthreads();

  // Phase 2a: publish block aggregate.
  if (tid < PP) {
    const int p = tid;
    const float a = 1.0f - fmaxf(w[p], 0.0f);
    float a16 = a;
#pragma unroll
    for (int i = 0; i < 4; ++i) a16 *= a16;  // a^16
    float bf = 0.f;
#pragma unroll
    for (int g2 = 0; g2 < GPB; ++g2) bf = fmaf(a16, bf, sf[g2][p]);
    agg[((size_t)b * BPR + cg) * PP + p] = bf;
    __threadfence();  // device-scope: aggregate visible before flag
  }
  __syncthreads();
  if (tid == 0) {
    __hip_atomic_store(&flags[b * BPR + cg], 1, __ATOMIC_RELEASE,
                       __HIP_MEMORY_SCOPE_AGENT);
  }

  // Phase 2b: lookback — wait for predecessors, accumulate seed.
  if (tid < PP) {
    const int p = tid;
    const float a = 1.0f - fmaxf(w[p], 0.0f);
    float a16 = a;
#pragma unroll
    for (int i = 0; i < 4; ++i) a16 *= a16;  // a^16
    float a128 = a16;
#pragma unroll
    for (int i = 0; i < 3; ++i) a128 *= a128;  // a^128

    const int* fl = flags + b * BPR;
    for (int j = 0; j < cg; ++j) {
      while (__hip_atomic_load(&fl[j], __ATOMIC_ACQUIRE,
                               __HIP_MEMORY_SCOPE_AGENT) == 0)
        __builtin_amdgcn_s_sleep(2);
    }

    float hh = 0.f;
    const float* bp = agg + (size_t)b * BPR * PP + p;
    int j = 0;
    for (; j + 8 <= cg; j += 8) {  // batch loads to pipeline L2 latency
      const float v0 = bp[(size_t)(j + 0) * PP];
      const float v1 = bp[(size_t)(j + 1) * PP];
      const float v2 = bp[(size_t)(j + 2) * PP];
      const float v3 = bp[(size_t)(j + 3) * PP];
      const float v4 = bp[(size_t)(j + 4) * PP];
      const float v5 = bp[(size_t)(j + 5) * PP];
      const float v6 = bp[(size_t)(j + 6) * PP];
      const float v7 = bp[(size_t)(j + 7) * PP];
      hh = fmaf(a128, hh, v0);
      hh = fmaf(a128, hh, v1);
      hh = fmaf(a128, hh, v2);
      hh = fmaf(a128, hh, v3);
      hh = fmaf(a128, hh, v4);
      hh = fmaf(a128, hh, v5);
      hh = fmaf(a128, hh, v6);
      hh = fmaf(a128, hh, v7);
    }
    for (; j < cg; ++j) hh = fmaf(a128, hh, bp[(size_t)j * PP]);

#pragma unroll
    for (int g2 = 0; g2 < GPB; ++g2) {
      seed[g2][p] = hh;
      hh = fmaf(a16, hh, sf[g2][p]);
    }
  }
  __syncthreads();

  // Phase 3: emit from registers, seeded.
  h = reinterpret_cast<const f4*>(&seed[g][0])[l];
  f4* ov = reinterpret_cast<f4*>(out) + off;
#pragma unroll
  for (int t = 0; t < CHUNK; ++t) {
    h.x = fmaf(a4.x, h.x, xr[t].x);
    h.y = fmaf(a4.y, h.y, xr[t].y);
    h.z = fmaf(a4.z, h.z, xr[t].z);
    h.w = fmaf(a4.w, h.w, xr[t].w);
    __builtin_nontemporal_store(h, &ov[(size_t)t * (PP / 4)]);
  }
}

extern "C" void kernel_launch(void* const* d_in, const int* in_sizes, int n_in,
                              void* d_out, int out_size, void* d_ws, size_t ws_size,
                              hipStream_t stream) {
  const float* x = (const float*)d_in[0];
  const float* w = (const float*)d_in[1];
  float* out = (float*)d_out;
  int* flags = (int*)d_ws;                      // 8 KiB
  float* agg = (float*)((char*)d_ws + 16384);   // 1 MiB, 16 KiB-aligned region

  hipMemsetAsync(flags, 0, BB * BPR * sizeof(int), stream);
  k_scan<<<GRID, 256, 0, stream>>>(x, w, agg, flags, out);
}

// Round 7
// 182.675 us; speedup vs baseline: 6.8686x; 6.8686x over previous
//
#include <hip/hip_runtime.h>
#include <hip/hip_cooperative_groups.h>

// Diagonal RNN scan: h_t = a_p * h_{t-1} + x_t,  a_p = 1 - relu(w_p), h_{-1}=0.
// x (B=32, L=8192, P=128) fp32, w (P,) fp32, out (B,L,P) fp32.
// R7: single cooperative kernel. Phase1: stream x (cacheable), publish block
// aggregates. grid.sync(). Phase2: short batched lookback over predecessor
// aggregates (combine factor a^256). Phase3: re-stream x (nt, L3-hot), emit.

namespace coop = cooperative_groups;

typedef float f4 __attribute__((ext_vector_type(4)));

#define BB 32
#define LL 8192
#define PP 128
#define CHUNK 32                 // timesteps per 32-lane group
#define GPB 8                    // groups per block
#define BSTEPS (CHUNK * GPB)     // 256 timesteps per block
#define BPR (LL / BSTEPS)        // 32 blocks per batch-row
#define GRID (BB * BPR)          // 1024 blocks

__global__ __launch_bounds__(256) void k_scan(
    const float* __restrict__ x, const float* __restrict__ w,
    float* __restrict__ agg /* [B][BPR][P] */, float* __restrict__ out) {
  const int tid = threadIdx.x;
  const int g = tid >> 5;   // group -> chunk within block
  const int l = tid & 31;   // lane -> float4 index over P
  const int b = blockIdx.x / BPR;
  const int bc = blockIdx.x % BPR;
  const int c = bc * GPB + g;  // global chunk index in this batch row

  const f4 w4 = reinterpret_cast<const f4*>(w)[l];
  f4 a4;
  a4.x = 1.0f - fmaxf(w4.x, 0.0f);
  a4.y = 1.0f - fmaxf(w4.y, 0.0f);
  a4.z = 1.0f - fmaxf(w4.z, 0.0f);
  a4.w = 1.0f - fmaxf(w4.w, 0.0f);

  const size_t off = ((size_t)b * LL + (size_t)c * CHUNK) * (PP / 4) + l;
  const f4* xv = reinterpret_cast<const f4*>(x) + off;

  __shared__ float sf[GPB][PP];
  __shared__ float seed[GPB][PP];

  // ---- Phase 1: stream chunk (cacheable: keep x in L3), group-local final.
  {
    f4 h = (f4)(0.0f);
#pragma unroll 8
    for (int t = 0; t < CHUNK; ++t) {
      const f4 v = xv[(size_t)t * (PP / 4)];
      h.x = fmaf(a4.x, h.x, v.x);
      h.y = fmaf(a4.y, h.y, v.y);
      h.z = fmaf(a4.z, h.z, v.z);
      h.w = fmaf(a4.w, h.w, v.w);
    }
    reinterpret_cast<f4*>(&sf[g][0])[l] = h;
  }
  __syncthreads();

  if (tid < PP) {
    const int p = tid;
    const float a = 1.0f - fmaxf(w[p], 0.0f);
    float a32 = a;
#pragma unroll
    for (int i = 0; i < 5; ++i) a32 *= a32;  // a^32
    float bf = 0.f;
#pragma unroll
    for (int g2 = 0; g2 < GPB; ++g2) bf = fmaf(a32, bf, sf[g2][p]);
    agg[((size_t)b * BPR + bc) * PP + p] = bf;
  }

  coop::this_grid().sync();

  // ---- Phase 2: batched lookback over predecessor block aggregates.
  if (tid < PP) {
    const int p = tid;
    const float a = 1.0f - fmaxf(w[p], 0.0f);
    float a32 = a;
#pragma unroll
    for (int i = 0; i < 5; ++i) a32 *= a32;  // a^32
    float a256 = a32;
#pragma unroll
    for (int i = 0; i < 3; ++i) a256 *= a256;  // a^256

    float hh = 0.f;
    const float* bp = agg + (size_t)b * BPR * PP + p;
    int j = 0;
    for (; j + 8 <= bc; j += 8) {  // batch loads to pipeline L2 latency
      const float v0 = bp[(size_t)(j + 0) * PP];
      const float v1 = bp[(size_t)(j + 1) * PP];
      const float v2 = bp[(size_t)(j + 2) * PP];
      const float v3 = bp[(size_t)(j + 3) * PP];
      const float v4 = bp[(size_t)(j + 4) * PP];
      const float v5 = bp[(size_t)(j + 5) * PP];
      const float v6 = bp[(size_t)(j + 6) * PP];
      const float v7 = bp[(size_t)(j + 7) * PP];
      hh = fmaf(a256, hh, v0);
      hh = fmaf(a256, hh, v1);
      hh = fmaf(a256, hh, v2);
      hh = fmaf(a256, hh, v3);
      hh = fmaf(a256, hh, v4);
      hh = fmaf(a256, hh, v5);
      hh = fmaf(a256, hh, v6);
      hh = fmaf(a256, hh, v7);
    }
    for (; j < bc; ++j) hh = fmaf(a256, hh, bp[(size_t)j * PP]);

#pragma unroll
    for (int g2 = 0; g2 < GPB; ++g2) {
      seed[g2][p] = hh;
      hh = fmaf(a32, hh, sf[g2][p]);
    }
  }
  __syncthreads();

  // ---- Phase 3: re-stream chunk (nt: last use, L3-hot), seeded emit.
  f4 h = reinterpret_cast<const f4*>(&seed[g][0])[l];
  f4* ov = reinterpret_cast<f4*>(out) + off;
#pragma unroll 8
  for (int t = 0; t < CHUNK; ++t) {
    const f4 v = __builtin_nontemporal_load(&xv[(size_t)t * (PP / 4)]);
    h.x = fmaf(a4.x, h.x, v.x);
    h.y = fmaf(a4.y, h.y, v.y);
    h.z = fmaf(a4.z, h.z, v.z);
    h.w = fmaf(a4.w, h.w, v.w);
    __builtin_nontemporal_store(h, &ov[(size_t)t * (PP / 4)]);
  }
}

extern "C" void kernel_launch(void* const* d_in, const int* in_sizes, int n_in,
                              void* d_out, int out_size, void* d_ws, size_t ws_size,
                              hipStream_t stream) {
  const float* x = (const float*)d_in[0];
  const float* w = (const float*)d_in[1];
  float* out = (float*)d_out;
  float* agg = (float*)d_ws;  // 512 KiB

  void* args[] = {(void*)&x, (void*)&w, (void*)&agg, (void*)&out};
  hipLaunchCooperativeKernel((const void*)k_scan, dim3(GRID), dim3(256), args,
                             0, stream);
}

// Round 8
// 107.311 us; speedup vs baseline: 11.6924x; 1.7023x over previous
//
#include <hip/hip_runtime.h>

// Diagonal RNN scan: h_t = a_p * h_{t-1} + x_t,  a_p = 1 - relu(w_p), h_{-1}=0.
// x (B=32, L=8192, P=128) fp32, w (P,) fp32, out (B,L,P) fp32.
// R8: single-pass CHAINED scan. 256 co-resident blocks (32 rows x 8 segs of
// 1024 steps). Block (b,j) locally scans its segment, then waits only on
// (b,j-1)'s inclusive prefix (1 poller/block, 1 flag, <=7 hops/row), publishes
// its own prefix, seeds, re-reads x (L3-hot) and nt-emits. x read once.

typedef float f4 __attribute__((ext_vector_type(4)));

#define BB 32
#define LL 8192
#define PP 128
#define TPB 512
#define GROUPS 16                // 512 / 32 lanes
#define CHUNK 64                 // steps per group
#define BSTEPS (GROUPS * CHUNK)  // 1024 steps per block
#define BPR (LL / BSTEPS)        // 8 blocks per batch-row
#define GRID (BB * BPR)          // 256 blocks -> trivially co-resident

__global__ __launch_bounds__(TPB) void k_scan(
    const float* __restrict__ x, const float* __restrict__ w,
    float* __restrict__ prefix /* [GRID][P] */, int* __restrict__ flags /* [GRID*32] */,
    float* __restrict__ out) {
  const int tid = threadIdx.x;
  const int g = tid >> 5;
  const int l = tid & 31;
  const int b = blockIdx.x / BPR;
  const int j = blockIdx.x % BPR;
  const int me = blockIdx.x;

  const f4 w4 = reinterpret_cast<const f4*>(w)[l];
  f4 a4;
  a4.x = 1.0f - fmaxf(w4.x, 0.0f);
  a4.y = 1.0f - fmaxf(w4.y, 0.0f);
  a4.z = 1.0f - fmaxf(w4.z, 0.0f);
  a4.w = 1.0f - fmaxf(w4.w, 0.0f);

  const size_t s0 = (size_t)j * BSTEPS + (size_t)g * CHUNK;
  const size_t off = ((size_t)b * LL + s0) * (PP / 4) + l;
  const f4* xv = reinterpret_cast<const f4*>(x) + off;

  __shared__ float sf[GROUPS][PP];    // group finals -> later reused as seeds
  __shared__ float sseed[GROUPS][PP];

  // ---- Phase 1: local scan of this group's 64 steps (fills L3 with x).
  {
    f4 h = (f4)(0.0f);
#pragma unroll 8
    for (int t = 0; t < CHUNK; ++t) {
      const f4 v = xv[(size_t)t * (PP / 4)];
      h.x = fmaf(a4.x, h.x, v.x);
      h.y = fmaf(a4.y, h.y, v.y);
      h.z = fmaf(a4.z, h.z, v.z);
      h.w = fmaf(a4.w, h.w, v.w);
    }
    reinterpret_cast<f4*>(&sf[g][0])[l] = h;
  }
  __syncthreads();

  // ---- Phase 2: block aggregate, chain handoff, per-group seeds.
  float sd = 0.f;  // inclusive prefix of predecessor (per-channel, tid<128)
  if (tid < PP) {
    const int p = tid;
    const float a = 1.0f - fmaxf(w[p], 0.0f);
    float a64 = a;
#pragma unroll
    for (int i = 0; i < 6; ++i) a64 *= a64;  // a^64
    float aB = a64;
#pragma unroll
    for (int i = 0; i < 4; ++i) aB *= aB;    // a^1024

    float bf = 0.f;
#pragma unroll
    for (int g2 = 0; g2 < GROUPS; ++g2) bf = fmaf(a64, bf, sf[g2][p]);

    if (j > 0) {
      if (tid == 0) {
        while (__hip_atomic_load(&flags[(me - 1) * 32], __ATOMIC_ACQUIRE,
                                 __HIP_MEMORY_SCOPE_AGENT) == 0)
          __builtin_amdgcn_s_sleep(8);
      }
    }
    // (all tid<PP converge here; need the flag visible to whole block)
  }
  __syncthreads();  // after this, predecessor's prefix is published (acquire by tid0)

  if (tid < PP) {
    const int p = tid;
    const float a = 1.0f - fmaxf(w[p], 0.0f);
    float a64 = a;
#pragma unroll
    for (int i = 0; i < 6; ++i) a64 *= a64;  // a^64
    float aB = a64;
#pragma unroll
    for (int i = 0; i < 4; ++i) aB *= aB;    // a^1024

    float bf = 0.f;
#pragma unroll
    for (int g2 = 0; g2 < GROUPS; ++g2) bf = fmaf(a64, bf, sf[g2][p]);

    float incl;
    if (j > 0) {
      sd = __hip_atomic_load(&prefix[(size_t)(me - 1) * PP + p],
                             __ATOMIC_RELAXED, __HIP_MEMORY_SCOPE_AGENT);
      incl = fmaf(aB, sd, bf);
    } else {
      incl = bf;
    }
    __hip_atomic_store(&prefix[(size_t)me * PP + p], incl, __ATOMIC_RELAXED,
                       __HIP_MEMORY_SCOPE_AGENT);
  }
  __syncthreads();
  if (tid == 0 && j < BPR - 1) {
    __hip_atomic_store(&flags[me * 32], 1, __ATOMIC_RELEASE,
                       __HIP_MEMORY_SCOPE_AGENT);
  }

  // Per-group seeds (chain already released; this is local work).
  if (tid < PP) {
    const int p = tid;
    const float a = 1.0f - fmaxf(w[p], 0.0f);
    float a64 = a;
#pragma unroll
    for (int i = 0; i < 6; ++i) a64 *= a64;
    float s = sd;  // exclusive seed for group 0
#pragma unroll
    for (int g2 = 0; g2 < GROUPS; ++g2) {
      sseed[g2][p] = s;
      s = fmaf(a64, s, sf[g2][p]);
    }
  }
  __syncthreads();

  // ---- Phase 3: seeded re-scan (x from L3), nt emit.
  f4 h = reinterpret_cast<const f4*>(&sseed[g][0])[l];
  f4* ov = reinterpret_cast<f4*>(out) + off;
#pragma unroll 8
  for (int t = 0; t < CHUNK; ++t) {
    const f4 v = __builtin_nontemporal_load(&xv[(size_t)t * (PP / 4)]);
    h.x = fmaf(a4.x, h.x, v.x);
    h.y = fmaf(a4.y, h.y, v.y);
    h.z = fmaf(a4.z, h.z, v.z);
    h.w = fmaf(a4.w, h.w, v.w);
    __builtin_nontemporal_store(h, &ov[(size_t)t * (PP / 4)]);
  }
}

extern "C" void kernel_launch(void* const* d_in, const int* in_sizes, int n_in,
                              void* d_out, int out_size, void* d_ws, size_t ws_size,
                              hipStream_t stream) {
  const float* x = (const float*)d_in[0];
  const float* w = (const float*)d_in[1];
  float* out = (float*)d_out;
  int* flags = (int*)d_ws;                            // 32 KiB (padded flags)
  float* prefix = (float*)((char*)d_ws + 32768);      // 128 KiB

  hipMemsetAsync(flags, 0, GRID * 32 * sizeof(int), stream);
  k_scan<<<GRID, TPB, 0, stream>>>(x, w, prefix, flags, out);
}

// Round 9
// 74.022 us; speedup vs baseline: 16.9508x; 1.4497x over previous
//
#include <hip/hip_runtime.h>

// Diagonal RNN scan: h_t = a_p * h_{t-1} + x_t,  a_p = 1 - relu(w_p), h_{-1}=0.
// x (B=32, L=8192, P=128) fp32, w (P,) fp32, out (B,L,P) fp32.
// R9: sync-free 2-kernel, both passes lean/full-occupancy.
//  k1: stream x (cacheable -> fills L3), publish 8 group finals (from regs)
//      + 1 block aggregate per block. 128 MB HBM read, 9 MB write.
//  k2: seeds purely from aggregates (batched lookback, L2) + own group finals;
//      then single stream x (nt, L3-hot) -> out (nt). No register residency,
//      no recompute, ~40 VGPR -> 8 blocks/CU.

typedef float f4 __attribute__((ext_vector_type(4)));

#define BB 32
#define LL 8192
#define PP 128
#define TPB 256
#define CHUNK 16                 // timesteps per 32-lane group
#define GPB 8                    // groups per block
#define BSTEPS (CHUNK * GPB)     // 128 timesteps per block
#define BPR (LL / BSTEPS)        // 64 blocks per batch-row
#define GRID (BB * BPR)          // 2048 blocks

__device__ __forceinline__ f4 make_a4(const float* __restrict__ w, int l) {
  const f4 w4 = reinterpret_cast<const f4*>(w)[l];
  f4 a4;
  a4.x = 1.0f - fmaxf(w4.x, 0.0f);
  a4.y = 1.0f - fmaxf(w4.y, 0.0f);
  a4.z = 1.0f - fmaxf(w4.z, 0.0f);
  a4.w = 1.0f - fmaxf(w4.w, 0.0f);
  return a4;
}

// ---- k1: stream x, publish group finals + block aggregate ------------------
__global__ __launch_bounds__(TPB) void k1_aggs(
    const float* __restrict__ x, const float* __restrict__ w,
    float* __restrict__ gf /* [B][BPR][GPB][P] */,
    float* __restrict__ agg /* [B][BPR][P] */) {
  const int tid = threadIdx.x;
  const int g = tid >> 5;
  const int l = tid & 31;
  const int b = blockIdx.x / BPR;
  const int s = blockIdx.x % BPR;

  const f4 a4 = make_a4(w, l);

  const f4* xv = reinterpret_cast<const f4*>(x) +
                 ((size_t)b * LL + (size_t)s * BSTEPS + (size_t)g * CHUNK) * (PP / 4) + l;
  f4 h = (f4)(0.0f);
#pragma unroll
  for (int t = 0; t < CHUNK; ++t) {
    const f4 v = xv[(size_t)t * (PP / 4)];  // cacheable: want x in L3 for k2
    h.x = fmaf(a4.x, h.x, v.x);
    h.y = fmaf(a4.y, h.y, v.y);
    h.z = fmaf(a4.z, h.z, v.z);
    h.w = fmaf(a4.w, h.w, v.w);
  }

  // group final straight from registers to global (coalesced f4)
  reinterpret_cast<f4*>(gf)[(((size_t)b * BPR + s) * GPB + g) * (PP / 4) + l] = h;

  __shared__ float sf[GPB][PP];
  reinterpret_cast<f4*>(&sf[g][0])[l] = h;
  __syncthreads();

  if (tid < PP) {
    const int p = tid;
    const float a = 1.0f - fmaxf(w[p], 0.0f);
    float a16 = a;
#pragma unroll
    for (int i = 0; i < 4; ++i) a16 *= a16;  // a^16
    float bf = 0.f;
#pragma unroll
    for (int g2 = 0; g2 < GPB; ++g2) bf = fmaf(a16, bf, sf[g2][p]);
    agg[((size_t)b * BPR + s) * PP + p] = bf;
  }
}

// ---- k2: seeds from aggregates, then single stream x -> out ----------------
__global__ __launch_bounds__(TPB) void k2_emit(
    const float* __restrict__ x, const float* __restrict__ w,
    const float* __restrict__ gf /* [B][BPR][GPB][P] */,
    const float* __restrict__ agg /* [B][BPR][P] */,
    float* __restrict__ out) {
  const int tid = threadIdx.x;
  const int g = tid >> 5;
  const int l = tid & 31;
  const int b = blockIdx.x / BPR;
  const int s = blockIdx.x % BPR;

  __shared__ float seed[GPB][PP];

  if (tid < PP) {
    const int p = tid;
    const float a = 1.0f - fmaxf(w[p], 0.0f);
    float a16 = a;
#pragma unroll
    for (int i = 0; i < 4; ++i) a16 *= a16;  // a^16
    float a128 = a16;
#pragma unroll
    for (int i = 0; i < 3; ++i) a128 *= a128;  // a^128

    // exclusive block prefix via batched lookback over predecessor aggregates
    float hh = 0.f;
    const float* bp = agg + (size_t)b * BPR * PP + p;
    int j = 0;
    for (; j + 8 <= s; j += 8) {
      const float v0 = bp[(size_t)(j + 0) * PP];
      const float v1 = bp[(size_t)(j + 1) * PP];
      const float v2 = bp[(size_t)(j + 2) * PP];
      const float v3 = bp[(size_t)(j + 3) * PP];
      const float v4 = bp[(size_t)(j + 4) * PP];
      const float v5 = bp[(size_t)(j + 5) * PP];
      const float v6 = bp[(size_t)(j + 6) * PP];
      const float v7 = bp[(size_t)(j + 7) * PP];
      hh = fmaf(a128, hh, v0);
      hh = fmaf(a128, hh, v1);
      hh = fmaf(a128, hh, v2);
      hh = fmaf(a128, hh, v3);
      hh = fmaf(a128, hh, v4);
      hh = fmaf(a128, hh, v5);
      hh = fmaf(a128, hh, v6);
      hh = fmaf(a128, hh, v7);
    }
    for (; j < s; ++j) hh = fmaf(a128, hh, bp[(size_t)j * PP]);

    // extend over own block's group finals -> per-group exclusive seeds
    const float* gp = gf + ((size_t)b * BPR + s) * GPB * PP + p;
#pragma unroll
    for (int g2 = 0; g2 < GPB; ++g2) {
      seed[g2][p] = hh;
      hh = fmaf(a16, hh, gp[(size_t)g2 * PP]);
    }
  }
  __syncthreads();

  const f4 a4 = make_a4(w, l);
  f4 h = reinterpret_cast<const f4*>(&seed[g][0])[l];

  const size_t off = ((size_t)b * LL + (size_t)s * BSTEPS + (size_t)g * CHUNK) * (PP / 4) + l;
  const f4* xv = reinterpret_cast<const f4*>(x) + off;
  f4* ov = reinterpret_cast<f4*>(out) + off;
#pragma unroll
  for (int t = 0; t < CHUNK; ++t) {
    const f4 v = __builtin_nontemporal_load(&xv[(size_t)t * (PP / 4)]);  // L3-hot
    h.x = fmaf(a4.x, h.x, v.x);
    h.y = fmaf(a4.y, h.y, v.y);
    h.z = fmaf(a4.z, h.z, v.z);
    h.w = fmaf(a4.w, h.w, v.w);
    __builtin_nontemporal_store(h, &ov[(size_t)t * (PP / 4)]);
  }
}

extern "C" void kernel_launch(void* const* d_in, const int* in_sizes, int n_in,
                              void* d_out, int out_size, void* d_ws, size_t ws_size,
                              hipStream_t stream) {
  const float* x = (const float*)d_in[0];
  const float* w = (const float*)d_in[1];
  float* out = (float*)d_out;
  float* gf = (float*)d_ws;                                   // 8 MiB
  float* agg = gf + (size_t)BB * BPR * GPB * PP;              // 1 MiB

  k1_aggs<<<GRID, TPB, 0, stream>>>(x, w, gf, agg);
  k2_emit<<<GRID, TPB, 0, stream>>>(x, w, gf, agg, out);
}